// Round 2
// baseline (748.400 us; speedup 1.0000x reference)
//
#include <hip/hip_runtime.h>
#include <hip/hip_bf16.h>

// scores[u,i] = -(||U[u]||^2 + ||I[i]||^2 - 2 U[u].I[i])
// M=256 users (gathered), N=500000 items, K=64. fp32 in/out.
// bf16 MFMA cross term; fp32 norms. Memory-bound on the 512 MB output.
//
// R2 design: block tile = 64 users x 256 items (user-group = blockIdx&3).
//  - acc reused per item-tile -> ~100 VGPRs, no spills
//  - B frags loaded straight from global fp32 in MFMA lane layout, bf16
//    convert in-register; i_sq via shfl_xor. No LDS staging, no barriers.
//  - each block writes 1 KB contiguous per output row over only 64 rows
//    (vs 256 B over 256 rows in R1) -> DRAM page / TLB locality.

#define DIM 64
#define NSCORE 256

typedef short bf16x8 __attribute__((ext_vector_type(8)));
typedef float f32x4 __attribute__((ext_vector_type(4)));

__device__ __forceinline__ short f2bf(float f) {
    union { float f; unsigned u; } v; v.f = f;
    unsigned r = v.u + 0x7FFF + ((v.u >> 16) & 1);   // RTN-even
    return (short)(r >> 16);
}

// Prep: gather 256 users, u_sq (fp32), write A bf16 in MFMA-fragment order:
// ws_A elem offset = (ut*2+ks)*512 + lane*8 + j,  lane = quad*16 + (u&15),
// where for element k of user u: ks=k>>5, quad=(k&31)>>3, j=k&7, ut=u>>4.
// (verified correct in R1: absmax 2.0 pass)
__global__ void prep_users(const int* __restrict__ uid,
                           const float* __restrict__ U,
                           short* __restrict__ wsA,
                           float* __restrict__ ws_usq) {
    int t = blockIdx.x * blockDim.x + threadIdx.x;   // 0..4095
    int u   = t >> 4;
    int seg = t & 15;
    int id = uid[u];
    float4 x = *(const float4*)(U + (long)id * DIM + seg * 4);
    float s = x.x * x.x + x.y * x.y + x.z * x.z + x.w * x.w;
    #pragma unroll
    for (int off = 1; off < 16; off <<= 1) s += __shfl_xor(s, off, 16);
    if (seg == 0) ws_usq[u] = s;

    int ks   = seg >> 3;
    int quad = (seg & 7) >> 1;
    int j0   = (seg & 1) * 4;
    int ut   = u >> 4;
    int lane = quad * 16 + (u & 15);
    short4 b;
    b.x = f2bf(x.x); b.y = f2bf(x.y); b.z = f2bf(x.z); b.w = f2bf(x.w);
    *(short4*)(wsA + (ut * 2 + ks) * 512 + lane * 8 + j0) = b;
}

__global__ __launch_bounds__(256)
void cml_main(const float* __restrict__ I,
              const short* __restrict__ wsA,
              const float* __restrict__ ws_usq,
              float* __restrict__ out,
              int n_items) {
    int t  = threadIdx.x;
    int ug = blockIdx.x & 3;        // user group: 64 users
    int ig = blockIdx.x >> 2;       // item chunk: 256 items
    int i0 = ig * 256;

    int w    = t >> 6;              // wave: items [i0+64w, i0+64w+64)
    int l    = t & 63;
    int m16  = l & 15;
    int quad = l >> 4;

    // A fragments for this user group (32 KB array, L1/L2-hot): a[ut][ks]
    bf16x8 a[4][2];
    const bf16x8* Af = (const bf16x8*)wsA;
    #pragma unroll
    for (int ut = 0; ut < 4; ut++)
        #pragma unroll
        for (int ks = 0; ks < 2; ks++)
            a[ut][ks] = Af[((ug * 4 + ut) * 2 + ks) * 64 + l];

    // u_sq for this lane's 16 output rows (L2-hot 1 KB)
    float us[4][4];
    #pragma unroll
    for (int ut = 0; ut < 4; ut++)
        #pragma unroll
        for (int r = 0; r < 4; r++)
            us[ut][r] = ws_usq[ug * 64 + ut * 16 + quad * 4 + r];

    size_t row0 = (size_t)(ug * 64 + quad * 4) * n_items;

    #pragma unroll
    for (int it = 0; it < 4; it++) {
        int gi = i0 + w * 64 + it * 16 + m16;       // this lane's item row
        const float* rp = I + (size_t)gi * DIM + quad * 8;
        float4 x0 = make_float4(0.f,0.f,0.f,0.f), x1 = x0, x2 = x0, x3 = x0;
        if (gi < n_items) {
            x0 = *(const float4*)(rp);          // dims quad*8 + 0..3
            x1 = *(const float4*)(rp + 4);      // dims quad*8 + 4..7
            x2 = *(const float4*)(rp + 32);     // dims 32+quad*8 + 0..3
            x3 = *(const float4*)(rp + 36);     // dims 32+quad*8 + 4..7
        }
        // i_sq: this lane covers 16 of the 64 dims; lanes sharing m16
        // (quad 0..3) cover all 64 -> reduce across bits 4,5 of lane id.
        float s = x0.x*x0.x + x0.y*x0.y + x0.z*x0.z + x0.w*x0.w
                + x1.x*x1.x + x1.y*x1.y + x1.z*x1.z + x1.w*x1.w
                + x2.x*x2.x + x2.y*x2.y + x2.z*x2.z + x2.w*x2.w
                + x3.x*x3.x + x3.y*x3.y + x3.z*x3.z + x3.w*x3.w;
        s += __shfl_xor(s, 16);
        s += __shfl_xor(s, 32);

        bf16x8 b0, b1;
        b0[0]=f2bf(x0.x); b0[1]=f2bf(x0.y); b0[2]=f2bf(x0.z); b0[3]=f2bf(x0.w);
        b0[4]=f2bf(x1.x); b0[5]=f2bf(x1.y); b0[6]=f2bf(x1.z); b0[7]=f2bf(x1.w);
        b1[0]=f2bf(x2.x); b1[1]=f2bf(x2.y); b1[2]=f2bf(x2.z); b1[3]=f2bf(x2.w);
        b1[4]=f2bf(x3.x); b1[5]=f2bf(x3.y); b1[6]=f2bf(x3.z); b1[7]=f2bf(x3.w);

        f32x4 acc[4];
        #pragma unroll
        for (int ut = 0; ut < 4; ut++) {
            acc[ut] = (f32x4){0.f, 0.f, 0.f, 0.f};
            acc[ut] = __builtin_amdgcn_mfma_f32_16x16x32_bf16(a[ut][0], b0, acc[ut], 0, 0, 0);
            acc[ut] = __builtin_amdgcn_mfma_f32_16x16x32_bf16(a[ut][1], b1, acc[ut], 0, 0, 0);
        }

        // Epilogue: C/D layout col=lane&15 (item), row=quad*4+r (user).
        if (gi < n_items) {
            #pragma unroll
            for (int ut = 0; ut < 4; ut++) {
                #pragma unroll
                for (int r = 0; r < 4; r++) {
                    out[row0 + (size_t)(ut * 16 + r) * n_items + gi] =
                        2.0f * acc[ut][r] - us[ut][r] - s;
                }
            }
        }
    }
}

extern "C" void kernel_launch(void* const* d_in, const int* in_sizes, int n_in,
                              void* d_out, int out_size, void* d_ws, size_t ws_size,
                              hipStream_t stream) {
    const int*   uid = (const int*)d_in[0];
    const float* U   = (const float*)d_in[1];
    const float* I   = (const float*)d_in[2];
    float*       out = (float*)d_out;
    int n_items = in_sizes[2] / DIM;

    short* wsA    = (short*)d_ws;
    float* ws_usq = (float*)((char*)d_ws + (size_t)NSCORE * DIM * sizeof(short));

    prep_users<<<16, 256, 0, stream>>>(uid, U, wsA, ws_usq);
    int nig = (n_items + 255) / 256;
    cml_main<<<nig * 4, 256, 0, stream>>>(I, wsA, ws_usq, out, n_items);
}